// Round 8
// baseline (249.369 us; speedup 1.0000x reference)
//
#include <hip/hip_runtime.h>
#include <hip/hip_bf16.h>

// Problem constants (from reference)
#define BATCH_N   16384
#define FEAT      128      // MOVIE_FEAT == USER_FEAT
#define NNBR      50
#define NUM_MOVIES_N 100000

typedef short  short8  __attribute__((ext_vector_type(8)));
typedef float  floatx4 __attribute__((ext_vector_type(4)));
typedef unsigned int u32;

__device__ __forceinline__ __hip_bfloat16 f2bf(float x) { return __float2bfloat16(x); }
__device__ __forceinline__ float bfb2f(short s) {
  union { u32 u; float f; } c; c.u = ((u32)(unsigned short)s) << 16; return c.f;
}

__device__ __forceinline__ floatx4 mfma16(short8 a, short8 b, floatx4 c) {
  return __builtin_amdgcn_mfma_f32_16x16x32_bf16(a, b, c, 0, 0, 0);
}

// ---------------------------------------------------------------------------
// conv_table: fp32 movie_table -> bf16 copy (25 MB, L2/L3-resident for gathers)
// ---------------------------------------------------------------------------
__global__ __launch_bounds__(256) void conv_table(
    const float* __restrict__ t, __hip_bfloat16* __restrict__ tb) {
  size_t i = ((size_t)blockIdx.x * 256 + threadIdx.x) * 8;
  float4 v0 = *(const float4*)(t + i);
  float4 v1 = *(const float4*)(t + i + 4);
  __hip_bfloat16 o[8];
  o[0] = f2bf(v0.x); o[1] = f2bf(v0.y); o[2] = f2bf(v0.z); o[3] = f2bf(v0.w);
  o[4] = f2bf(v1.x); o[5] = f2bf(v1.y); o[6] = f2bf(v1.z); o[7] = f2bf(v1.w);
  *(short8*)(tb + i) = *(short8*)o;
}

// ---------------------------------------------------------------------------
// prep: bf16 transposed weights Wt[n][k] + fused bias bu+bm.
// WcatT=[Wu;Wm]^T [256n][256k]; W1T [256][256]; W2T [128n][256k]; WmT [256n][128k]
// ---------------------------------------------------------------------------
__global__ __launch_bounds__(256) void prep_kernel(
    const float* __restrict__ Wu, const float* __restrict__ Wm,
    const float* __restrict__ W1, const float* __restrict__ W2,
    const float* __restrict__ bu, const float* __restrict__ bm,
    __hip_bfloat16* __restrict__ WcatT, __hip_bfloat16* __restrict__ WmT,
    __hip_bfloat16* __restrict__ W1T,  __hip_bfloat16* __restrict__ W2T,
    float* __restrict__ bc) {
  int idx = blockIdx.x * 256 + threadIdx.x;   // 0..65535
  int n = idx & 255, k = idx >> 8;
  float v = (k < 128) ? Wu[k * 256 + n] : Wm[(k - 128) * 256 + n];
  WcatT[n * 256 + k] = f2bf(v);
  W1T[n * 256 + k]   = f2bf(W1[k * 256 + n]);
  if (k < 128) WmT[n * 128 + k] = f2bf(Wm[k * 256 + n]);
  if (idx < 32768) {
    int k2 = idx >> 7, n2 = idx & 127;
    W2T[n2 * 256 + k2] = f2bf(W2[k2 * 128 + n2]);
  }
  if (idx < 256) bc[idx] = bu[idx] + bm[idx];
}

// ---------------------------------------------------------------------------
// gather_user: one WAVE per batch row. Lane slice = 16 B; quad q handles
// nbr 4*it+q -> 13 wave-loads of 1 KB. Cross-quad shfl_xor reduce.
// ---------------------------------------------------------------------------
__global__ __launch_bounds__(256) void gather_user(
    const float* __restrict__ users, const int* __restrict__ nbr_ids,
    const __hip_bfloat16* __restrict__ tb, __hip_bfloat16* __restrict__ A_user) {
  int row  = (blockIdx.x << 2) + (threadIdx.x >> 6);
  int lane = threadIdx.x & 63;
  int quad = lane >> 4, sl = lane & 15;
  const int* nb = nbr_ids + row * NNBR;
  float acc[8] = {0.f, 0.f, 0.f, 0.f, 0.f, 0.f, 0.f, 0.f};
  #pragma unroll
  for (int it = 0; it < 13; ++it) {
    int j = it * 4 + quad;
    if (j < NNBR) {
      int id = nb[j];
      short8 v = *(const short8*)(tb + (size_t)id * FEAT + sl * 8);
      #pragma unroll
      for (int e = 0; e < 8; ++e) acc[e] += bfb2f(v[e]);
    }
  }
  __hip_bfloat16 o[8];
  #pragma unroll
  for (int e = 0; e < 8; ++e) {
    float v = acc[e];
    v += __shfl_xor(v, 16, 64);
    v += __shfl_xor(v, 32, 64);
    o[e] = f2bf(v * (1.f / NNBR));
  }
  if (quad == 0)
    *(short8*)(A_user + (size_t)row * 256 + 128 + sl * 8) = *(short8*)o;
  float2 uv = ((const float2*)(users + (size_t)row * FEAT))[lane];
  __hip_bfloat162 t0; t0.x = f2bf(uv.x); t0.y = f2bf(uv.y);
  ((__hip_bfloat162*)(A_user + (size_t)row * 256))[lane] = t0;
}

// ---------------------------------------------------------------------------
// gemm_bv: barrier-free GEMM; B in VGPRs; A direct from global with L1 reuse.
//   C[M][NTOT] = act(A[M][K0] @ Wt^T + bias)
// Block = 512 thr = 8 waves covering the FULL NTOT (wave w owns JN*16 cols at
// w*JN*16; JN = NTOT/128). R7 lesson: splitting N across blocks made each A
// row be fetched 8x from L3 (~200 MB -> ~40 us for L1-layer). Here all 8
// waves of the one block covering a row read the SAME 16-row, 8 KB A tile ->
// after the first wave it is L1-resident (32 KB L1), so L2/L3 A traffic is
// ~1x (25 MB). B frags (JN x KK short8) persist in VGPRs, loaded once per
// block from the L2-hot weight table. A-frags register-double-buffered one
// iter ahead (16 MFMAs = ~256 SIMD-cy cover the prefetch latency).
// Grid = 256 blocks exactly -> 1 block/CU, 2 waves/SIMD;
// __launch_bounds__(512,2) -> 256-VGPR cap so the ~155-VGPR set is resident.
// GATHER (layer-0 pos/neg): A row = tb[ids[m]].
// ---------------------------------------------------------------------------
template <int K0, int NTOT, bool GATHER, bool RELU, bool OUTF32, int IT>
__global__ __launch_bounds__(512, 2) void gemm_bv(
    const __hip_bfloat16* __restrict__ Asrc,
    const int* __restrict__ pos_ids, const int* __restrict__ neg_ids,
    const __hip_bfloat16* __restrict__ Wt, const float* __restrict__ bias,
    float* __restrict__ Cf, __hip_bfloat16* __restrict__ Cb) {
  constexpr int KK = K0 / 32;
  constexpr int JN = NTOT / 128;         // 16-col j-tiles per wave (2 or 1)
  const int lane = threadIdx.x & 63, wid = threadIdx.x >> 6;   // wid 0..7
  const int quad = lane >> 4, lrow = lane & 15;
  const int c0 = wid * JN * 16;
  const long mbase = (long)blockIdx.x * (16 * IT);

  // persistent B fragments for this wave's columns (JN*KK short8 VGPRs)
  short8 bfr[JN][KK];
  float  bv[JN];
  #pragma unroll
  for (int j = 0; j < JN; ++j) {
    #pragma unroll
    for (int kc = 0; kc < KK; ++kc)
      bfr[j][kc] = *(const short8*)(Wt + (size_t)(c0 + j * 16 + lrow) * K0 +
                                    kc * 32 + quad * 8);
    bv[j] = bias[c0 + j * 16 + lrow];
  }

  short8 abuf[2][KK];
  auto loadA = [&](int it, short8* dst) {
    long m = mbase + it * 16 + lrow;
    const __hip_bfloat16* rp;
    if (GATHER) {
      int id = (m < BATCH_N) ? pos_ids[m] : neg_ids[m - BATCH_N];
      rp = Asrc + (size_t)id * K0;
    } else {
      rp = Asrc + (size_t)m * K0;
    }
    #pragma unroll
    for (int kc = 0; kc < KK; ++kc)
      dst[kc] = *(const short8*)(rp + kc * 32 + quad * 8);
  };

  loadA(0, abuf[0]);
  #pragma unroll
  for (int it = 0; it < IT; ++it) {
    if (it + 1 < IT) loadA(it + 1, abuf[(it + 1) & 1]);
    const short8* af = abuf[it & 1];
    floatx4 pa[JN], pb[JN];
    #pragma unroll
    for (int j = 0; j < JN; ++j) { pa[j] = {}; pb[j] = {}; }
    #pragma unroll
    for (int kc = 0; kc < KK; kc += 2)
      #pragma unroll
      for (int j = 0; j < JN; ++j) {
        pa[j] = mfma16(af[kc],     bfr[j][kc],     pa[j]);
        pb[j] = mfma16(af[kc + 1], bfr[j][kc + 1], pb[j]);
      }
    long m0 = mbase + it * 16;
    #pragma unroll
    for (int j = 0; j < JN; ++j) {
      floatx4 a = pa[j] + pb[j];
      int col = c0 + j * 16 + lrow;
      #pragma unroll
      for (int r = 0; r < 4; ++r) {
        long row = m0 + quad * 4 + r;
        float v = a[r] + bv[j];
        if (RELU) v = fmaxf(v, 0.f);
        if (OUTF32) Cf[row * NTOT + col] = v;
        else        Cb[row * NTOT + col] = f2bf(v);
      }
    }
  }
}

// ---------------------------------------------------------------------------
extern "C" void kernel_launch(void* const* d_in, const int* in_sizes, int n_in,
                              void* d_out, int out_size, void* d_ws, size_t ws_size,
                              hipStream_t stream) {
  const float* users   = (const float*)d_in[0];
  // d_in[1] pos_movies, d_in[2] neg_movies, d_in[3] user_ids: unused by ref
  const int*   pos_ids = (const int*)d_in[4];
  const int*   neg_ids = (const int*)d_in[5];
  const int*   nbr_ids = (const int*)d_in[6];
  const float* table   = (const float*)d_in[7];
  const float* Wu = (const float*)d_in[8];
  const float* bu = (const float*)d_in[9];
  const float* Wm = (const float*)d_in[10];
  const float* bm = (const float*)d_in[11];
  const float* W1 = (const float*)d_in[12];
  const float* b1 = (const float*)d_in[13];
  const float* W2 = (const float*)d_in[14];
  const float* b2 = (const float*)d_in[15];
  float* out = (float*)d_out;

  // workspace carve (all 256B aligned). Total ~83 MB.
  char* p = (char*)d_ws;
  auto carve = [&](size_t bytes) { char* r = p; p += (bytes + 255) & ~(size_t)255; return r; };
  __hip_bfloat16* tb     = (__hip_bfloat16*)carve((size_t)NUM_MOVIES_N * FEAT * 2);
  __hip_bfloat16* WcatT  = (__hip_bfloat16*)carve(256 * 256 * 2);
  __hip_bfloat16* WmT    = (__hip_bfloat16*)carve(256 * 128 * 2);
  __hip_bfloat16* W1T    = (__hip_bfloat16*)carve(256 * 256 * 2);
  __hip_bfloat16* W2T    = (__hip_bfloat16*)carve(128 * 256 * 2);
  float*          bc     = (float*)carve(256 * 4);
  __hip_bfloat16* A_user = (__hip_bfloat16*)carve((size_t)BATCH_N * 256 * 2);
  __hip_bfloat16* E      = (__hip_bfloat16*)carve((size_t)3 * BATCH_N * 256 * 2);
  __hip_bfloat16* H      = (__hip_bfloat16*)carve((size_t)3 * BATCH_N * 256 * 2);

  conv_table<<<NUM_MOVIES_N * FEAT / (256 * 8), 256, 0, stream>>>(table, tb);
  prep_kernel<<<256, 256, 0, stream>>>(Wu, Wm, W1, W2, bu, bm,
                                       WcatT, WmT, W1T, W2T, bc);
  gather_user<<<BATCH_N / 4, 256, 0, stream>>>(users, nbr_ids, tb, A_user);

  // E rows: [0,B) user | [B,2B) pos | [2B,3B) neg.  All grids = 256 blocks.
  // L0-user: E[0:B] = A_user @ WcatT^T + bc    (M=16384, K=256, N=256)
  gemm_bv<256, 256, false, false, false, 4>
      <<<256, 512, 0, stream>>>(A_user, nullptr, nullptr, WcatT, bc,
                                nullptr, E);
  // L0-pn: E[B:3B] = tb[ids] @ WmT^T + bm      (M=32768, K=128, N=256)
  gemm_bv<128, 256, true, false, false, 8>
      <<<256, 512, 0, stream>>>(tb, pos_ids, neg_ids, WmT, bm,
                                nullptr, E + (size_t)BATCH_N * 256);
  // L1: H = relu(E @ W1T^T + b1)               (M=49152, K=256, N=256)
  gemm_bv<256, 256, false, true, false, 12>
      <<<256, 512, 0, stream>>>(E, nullptr, nullptr, W1T, b1,
                                nullptr, H);
  // L2: out = relu(H @ W2T^T + b2)             (M=49152, K=256, N=128)
  gemm_bv<256, 128, false, true, true, 12>
      <<<256, 512, 0, stream>>>(H, nullptr, nullptr, W2T, b2,
                                out, nullptr);
}

// Round 9
// 205.905 us; speedup vs baseline: 1.2111x; 1.2111x over previous
//
#include <hip/hip_runtime.h>
#include <hip/hip_bf16.h>

// Problem constants (from reference)
#define BATCH_N   16384
#define FEAT      128      // MOVIE_FEAT == USER_FEAT
#define NNBR      50
#define NUM_MOVIES_N 100000

typedef short  short8  __attribute__((ext_vector_type(8)));
typedef float  floatx4 __attribute__((ext_vector_type(4)));
typedef unsigned int u32;

__device__ __forceinline__ __hip_bfloat16 f2bf(float x) { return __float2bfloat16(x); }
__device__ __forceinline__ float bfb2f(short s) {
  union { u32 u; float f; } c; c.u = ((u32)(unsigned short)s) << 16; return c.f;
}

// async global->LDS 16B DMA. LDS dst must be wave-uniform base + lane*16
// (m104), so the XOR swizzle is applied to the SOURCE index.
__device__ __forceinline__ void gld16(const __hip_bfloat16* g, __hip_bfloat16* l) {
  __builtin_amdgcn_global_load_lds(
      (const __attribute__((address_space(1))) u32*)g,
      (__attribute__((address_space(3))) u32*)l, 16, 0, 0);
}

__device__ __forceinline__ floatx4 mfma16(short8 a, short8 b, floatx4 c) {
  return __builtin_amdgcn_mfma_f32_16x16x32_bf16(a, b, c, 0, 0, 0);
}

// ---------------------------------------------------------------------------
// conv_table: fp32 movie_table -> bf16 copy (25 MB, cache-friendly gathers)
// ---------------------------------------------------------------------------
__global__ __launch_bounds__(256) void conv_table(
    const float* __restrict__ t, __hip_bfloat16* __restrict__ tb) {
  size_t i = ((size_t)blockIdx.x * 256 + threadIdx.x) * 8;
  float4 v0 = *(const float4*)(t + i);
  float4 v1 = *(const float4*)(t + i + 4);
  __hip_bfloat16 o[8];
  o[0] = f2bf(v0.x); o[1] = f2bf(v0.y); o[2] = f2bf(v0.z); o[3] = f2bf(v0.w);
  o[4] = f2bf(v1.x); o[5] = f2bf(v1.y); o[6] = f2bf(v1.z); o[7] = f2bf(v1.w);
  *(short8*)(tb + i) = *(short8*)o;
}

// ---------------------------------------------------------------------------
// prep: bf16 transposed weights Wt[n][k] + fused bias bu+bm.
// WcatT=[Wu;Wm]^T [256n][256k]; W1T [256][256]; W2T [128n][256k]; WmT [256n][128k]
// ---------------------------------------------------------------------------
__global__ __launch_bounds__(256) void prep_kernel(
    const float* __restrict__ Wu, const float* __restrict__ Wm,
    const float* __restrict__ W1, const float* __restrict__ W2,
    const float* __restrict__ bu, const float* __restrict__ bm,
    __hip_bfloat16* __restrict__ WcatT, __hip_bfloat16* __restrict__ WmT,
    __hip_bfloat16* __restrict__ W1T,  __hip_bfloat16* __restrict__ W2T,
    float* __restrict__ bc) {
  int idx = blockIdx.x * 256 + threadIdx.x;   // 0..65535
  int n = idx & 255, k = idx >> 8;
  float v = (k < 128) ? Wu[k * 256 + n] : Wm[(k - 128) * 256 + n];
  WcatT[n * 256 + k] = f2bf(v);
  W1T[n * 256 + k]   = f2bf(W1[k * 256 + n]);
  if (k < 128) WmT[n * 128 + k] = f2bf(Wm[k * 256 + n]);
  if (idx < 32768) {
    int k2 = idx >> 7, n2 = idx & 127;
    W2T[n2 * 256 + k2] = f2bf(W2[k2 * 128 + n2]);
  }
  if (idx < 256) bc[idx] = bu[idx] + bm[idx];
}

// ---------------------------------------------------------------------------
// gather_user: one WAVE per batch row. Lane slice = 16 B; quad q handles
// nbr 4*it+q -> 13 wave-loads of 1 KB. Cross-quad shfl_xor reduce.
// ---------------------------------------------------------------------------
__global__ __launch_bounds__(256) void gather_user(
    const float* __restrict__ users, const int* __restrict__ nbr_ids,
    const __hip_bfloat16* __restrict__ tb, __hip_bfloat16* __restrict__ A_user) {
  int row  = (blockIdx.x << 2) + (threadIdx.x >> 6);
  int lane = threadIdx.x & 63;
  int quad = lane >> 4, sl = lane & 15;
  const int* nb = nbr_ids + row * NNBR;
  float acc[8] = {0.f, 0.f, 0.f, 0.f, 0.f, 0.f, 0.f, 0.f};
  #pragma unroll
  for (int it = 0; it < 13; ++it) {
    int j = it * 4 + quad;
    if (j < NNBR) {
      int id = nb[j];
      short8 v = *(const short8*)(tb + (size_t)id * FEAT + sl * 8);
      #pragma unroll
      for (int e = 0; e < 8; ++e) acc[e] += bfb2f(v[e]);
    }
  }
  __hip_bfloat16 o[8];
  #pragma unroll
  for (int e = 0; e < 8; ++e) {
    float v = acc[e];
    v += __shfl_xor(v, 16, 64);
    v += __shfl_xor(v, 32, 64);
    o[e] = f2bf(v * (1.f / NNBR));
  }
  if (quad == 0)
    *(short8*)(A_user + (size_t)row * 256 + 128 + sl * 8) = *(short8*)o;
  float2 uv = ((const float2*)(users + (size_t)row * FEAT))[lane];
  __hip_bfloat162 t0; t0.x = f2bf(uv.x); t0.y = f2bf(uv.y);
  ((__hip_bfloat162*)(A_user + (size_t)row * 256))[lane] = t0;
}

// ---------------------------------------------------------------------------
// gemm_lds: B weights persistent in VGPRs; A staged through an LDS double
// buffer in 64-row chunks.   C[M][NTOT] = act(A[M][K0] @ Wt^T + bias)
//
// R8 lesson: register-double-buffered A (abuf 128 VGPRs) + persistent B
// (128 VGPRs) overflowed the 256-VGPR cap for the K=256,N=256 layers -> the
// compiler sank the loads and the loop ran latency-exposed. Moving A to LDS
// drops the register need to ~210 and adds x8 cross-wave reuse of each tile.
//
// Block = 512 thr = 8 waves covering the FULL NTOT (wave w owns JN*16 cols).
// Pipeline per 64-row chunk (one barrier per chunk):
//   __syncthreads()  -> vmcnt(0) drain: buf[cur] staged, buf[nxt] readers done
//   issue async stage of chunk+1 into buf[nxt]   (gld16, CPB per thread)
//   compute chunk from buf[cur]: 4 iters x (KK ds_read_b128 + 2*KK*JN MFMA)
// ~620 SIMD-cy of compute between stage-issue and the next drain hides the
// L2/L3 latency. Grid = 256 blocks = 1 block/CU (2 waves/SIMD, 256-VGPR cap).
// A-tile XOR swizzle: LDS slot s of row r holds global chunk s^(r&7)
// -> ds_read_b128 conflicts <=2-way (free, m136).
// GATHER (layer-0 pos/neg): A row m = tb[ids[m]].
// ---------------------------------------------------------------------------
template <int K0, int NTOT, bool GATHER, bool RELU, bool OUTF32, int NCHUNK>
__global__ __launch_bounds__(512, 2) void gemm_lds(
    const __hip_bfloat16* __restrict__ Asrc,
    const int* __restrict__ pos_ids, const int* __restrict__ neg_ids,
    const __hip_bfloat16* __restrict__ Wt, const float* __restrict__ bias,
    float* __restrict__ Cf, __hip_bfloat16* __restrict__ Cb) {
  constexpr int KK  = K0 / 32;           // 32-elem k-chunks (8 or 4)
  constexpr int JN  = NTOT / 128;        // 16-col j-tiles per wave (2 or 1)
  constexpr int SPR = K0 / 8;            // 16B slots per row (32 or 16)
  constexpr int CPB = 64 * SPR / 512;    // gld16 per thread per chunk (4 or 2)
  __shared__ __hip_bfloat16 Ast[2][64 * K0];

  const int t    = threadIdx.x;
  const int lane = t & 63, wid = t >> 6;         // wid 0..7
  const int quad = lane >> 4, lrow = lane & 15;
  const int c0   = wid * JN * 16;
  const long mbase = (long)blockIdx.x * (64 * NCHUNK);

  // persistent B fragments for this wave's columns (JN*KK short8)
  short8 bfr[JN][KK];
  float  bv[JN];
  #pragma unroll
  for (int j = 0; j < JN; ++j) {
    #pragma unroll
    for (int kc = 0; kc < KK; ++kc)
      bfr[j][kc] = *(const short8*)(Wt + (size_t)(c0 + j * 16 + lrow) * K0 +
                                    kc * 32 + quad * 8);
    bv[j] = bias[c0 + j * 16 + lrow];
  }

  auto stage = [&](int ch, int buf) {
    #pragma unroll
    for (int i = 0; i < CPB; ++i) {
      int c = t + i * 512;               // chunk index in buffer
      int r = c / SPR, s = c % SPR;      // row in [0,64), 16B slot
      long m = mbase + ch * 64 + r;
      const __hip_bfloat16* rp;
      if (GATHER) {
        int id = (m < BATCH_N) ? pos_ids[m] : neg_ids[m - BATCH_N];
        rp = Asrc + (size_t)id * K0;
      } else {
        rp = Asrc + (size_t)m * K0;
      }
      gld16(rp + ((s ^ (r & 7)) << 3), Ast[buf] + (c << 3));
    }
  };

  stage(0, 0);
  for (int ch = 0; ch < NCHUNK; ++ch) {
    __syncthreads();                     // drain: buf[ch&1] ready, other free
    if (ch + 1 < NCHUNK) stage(ch + 1, (ch + 1) & 1);
    const __hip_bfloat16* buf = Ast[ch & 1];

    #pragma unroll
    for (int it = 0; it < 4; ++it) {
      int r = it * 16 + lrow;
      short8 af[KK];
      #pragma unroll
      for (int kc = 0; kc < KK; ++kc)
        af[kc] = *(const short8*)&buf[r * K0 +
                                      (((kc * 4 + quad) ^ (r & 7)) << 3)];
      floatx4 pa[JN], pb[JN];
      #pragma unroll
      for (int j = 0; j < JN; ++j) { pa[j] = {}; pb[j] = {}; }
      #pragma unroll
      for (int kc = 0; kc < KK; kc += 2)
        #pragma unroll
        for (int j = 0; j < JN; ++j) {
          pa[j] = mfma16(af[kc],     bfr[j][kc],     pa[j]);
          pb[j] = mfma16(af[kc + 1], bfr[j][kc + 1], pb[j]);
        }
      long m0 = mbase + ch * 64 + it * 16;
      #pragma unroll
      for (int j = 0; j < JN; ++j) {
        floatx4 a = pa[j] + pb[j];
        int col = c0 + j * 16 + lrow;
        #pragma unroll
        for (int rr = 0; rr < 4; ++rr) {
          long row = m0 + quad * 4 + rr;
          float v = a[rr] + bv[j];
          if (RELU) v = fmaxf(v, 0.f);
          if (OUTF32) Cf[row * NTOT + col] = v;
          else        Cb[row * NTOT + col] = f2bf(v);
        }
      }
    }
  }
}

// ---------------------------------------------------------------------------
extern "C" void kernel_launch(void* const* d_in, const int* in_sizes, int n_in,
                              void* d_out, int out_size, void* d_ws, size_t ws_size,
                              hipStream_t stream) {
  const float* users   = (const float*)d_in[0];
  // d_in[1] pos_movies, d_in[2] neg_movies, d_in[3] user_ids: unused by ref
  const int*   pos_ids = (const int*)d_in[4];
  const int*   neg_ids = (const int*)d_in[5];
  const int*   nbr_ids = (const int*)d_in[6];
  const float* table   = (const float*)d_in[7];
  const float* Wu = (const float*)d_in[8];
  const float* bu = (const float*)d_in[9];
  const float* Wm = (const float*)d_in[10];
  const float* bm = (const float*)d_in[11];
  const float* W1 = (const float*)d_in[12];
  const float* b1 = (const float*)d_in[13];
  const float* W2 = (const float*)d_in[14];
  const float* b2 = (const float*)d_in[15];
  float* out = (float*)d_out;

  // workspace carve (all 256B aligned). Total ~83 MB.
  char* p = (char*)d_ws;
  auto carve = [&](size_t bytes) { char* r = p; p += (bytes + 255) & ~(size_t)255; return r; };
  __hip_bfloat16* tb     = (__hip_bfloat16*)carve((size_t)NUM_MOVIES_N * FEAT * 2);
  __hip_bfloat16* WcatT  = (__hip_bfloat16*)carve(256 * 256 * 2);
  __hip_bfloat16* WmT    = (__hip_bfloat16*)carve(256 * 128 * 2);
  __hip_bfloat16* W1T    = (__hip_bfloat16*)carve(256 * 256 * 2);
  __hip_bfloat16* W2T    = (__hip_bfloat16*)carve(128 * 256 * 2);
  float*          bc     = (float*)carve(256 * 4);
  __hip_bfloat16* A_user = (__hip_bfloat16*)carve((size_t)BATCH_N * 256 * 2);
  __hip_bfloat16* E      = (__hip_bfloat16*)carve((size_t)3 * BATCH_N * 256 * 2);
  __hip_bfloat16* H      = (__hip_bfloat16*)carve((size_t)3 * BATCH_N * 256 * 2);

  conv_table<<<NUM_MOVIES_N * FEAT / (256 * 8), 256, 0, stream>>>(table, tb);
  prep_kernel<<<256, 256, 0, stream>>>(Wu, Wm, W1, W2, bu, bm,
                                       WcatT, WmT, W1T, W2T, bc);
  gather_user<<<BATCH_N / 4, 256, 0, stream>>>(users, nbr_ids, tb, A_user);

  // E rows: [0,B) user | [B,2B) pos | [2B,3B) neg.  All grids = 256 blocks.
  // L0-user: E[0:B] = A_user @ WcatT^T + bc    (M=16384, K=256, N=256)
  gemm_lds<256, 256, false, false, false, 1>
      <<<256, 512, 0, stream>>>(A_user, nullptr, nullptr, WcatT, bc,
                                nullptr, E);
  // L0-pn: E[B:3B] = tb[ids] @ WmT^T + bm      (M=32768, K=128, N=256)
  gemm_lds<128, 256, true, false, false, 2>
      <<<256, 512, 0, stream>>>(tb, pos_ids, neg_ids, WmT, bm,
                                nullptr, E + (size_t)BATCH_N * 256);
  // L1: H = relu(E @ W1T^T + b1)               (M=49152, K=256, N=256)
  gemm_lds<256, 256, false, true, false, 3>
      <<<256, 512, 0, stream>>>(E, nullptr, nullptr, W1T, b1,
                                nullptr, H);
  // L2: out = relu(H @ W2T^T + b2)             (M=49152, K=256, N=128)
  gemm_lds<256, 128, false, true, true, 3>
      <<<256, 512, 0, stream>>>(H, nullptr, nullptr, W2T, b2,
                                out, nullptr);
}

// Round 10
// 204.185 us; speedup vs baseline: 1.2213x; 1.0084x over previous
//
#include <hip/hip_runtime.h>
#include <hip/hip_bf16.h>

// Problem constants (from reference)
#define BATCH_N   16384
#define FEAT      128      // MOVIE_FEAT == USER_FEAT
#define NNBR      50
#define NUM_MOVIES_N 100000

typedef short  short8  __attribute__((ext_vector_type(8)));
typedef float  floatx4 __attribute__((ext_vector_type(4)));
typedef unsigned int u32;

__device__ __forceinline__ __hip_bfloat16 f2bf(float x) { return __float2bfloat16(x); }
__device__ __forceinline__ float bfb2f(short s) {
  union { u32 u; float f; } c; c.u = ((u32)(unsigned short)s) << 16; return c.f;
}

// async global->LDS 16B DMA. LDS dst must be wave-uniform base + lane*16
// (m104), so the XOR swizzle is applied to the SOURCE index.
__device__ __forceinline__ void gld16(const __hip_bfloat16* g, __hip_bfloat16* l) {
  __builtin_amdgcn_global_load_lds(
      (const __attribute__((address_space(1))) u32*)g,
      (__attribute__((address_space(3))) u32*)l, 16, 0, 0);
}

__device__ __forceinline__ floatx4 mfma16(short8 a, short8 b, floatx4 c) {
  return __builtin_amdgcn_mfma_f32_16x16x32_bf16(a, b, c, 0, 0, 0);
}

// ---------------------------------------------------------------------------
// prep_all: fused (a) fp32 movie_table -> bf16 copy and (b) bf16 transposed
// weights Wt[n][k] + fused bias bu+bm. One launch instead of two.
// blocks [0,6250): conv;  [6250,6506): weight prep.
// ---------------------------------------------------------------------------
#define CONV_BLOCKS (NUM_MOVIES_N * FEAT / (256 * 8))   // 6250
__global__ __launch_bounds__(256) void prep_all(
    const float* __restrict__ t, __hip_bfloat16* __restrict__ tb,
    const float* __restrict__ Wu, const float* __restrict__ Wm,
    const float* __restrict__ W1, const float* __restrict__ W2,
    const float* __restrict__ bu, const float* __restrict__ bm,
    __hip_bfloat16* __restrict__ WcatT, __hip_bfloat16* __restrict__ WmT,
    __hip_bfloat16* __restrict__ W1T,  __hip_bfloat16* __restrict__ W2T,
    float* __restrict__ bc) {
  int bid = blockIdx.x;
  if (bid < CONV_BLOCKS) {
    size_t i = ((size_t)bid * 256 + threadIdx.x) * 8;
    float4 v0 = *(const float4*)(t + i);
    float4 v1 = *(const float4*)(t + i + 4);
    __hip_bfloat16 o[8];
    o[0] = f2bf(v0.x); o[1] = f2bf(v0.y); o[2] = f2bf(v0.z); o[3] = f2bf(v0.w);
    o[4] = f2bf(v1.x); o[5] = f2bf(v1.y); o[6] = f2bf(v1.z); o[7] = f2bf(v1.w);
    *(short8*)(tb + i) = *(short8*)o;
  } else {
    int idx = (bid - CONV_BLOCKS) * 256 + threadIdx.x;   // 0..65535
    int n = idx & 255, k = idx >> 8;
    float v = (k < 128) ? Wu[k * 256 + n] : Wm[(k - 128) * 256 + n];
    WcatT[n * 256 + k] = f2bf(v);
    W1T[n * 256 + k]   = f2bf(W1[k * 256 + n]);
    if (k < 128) WmT[n * 128 + k] = f2bf(Wm[k * 256 + n]);
    if (idx < 32768) {
      int k2 = idx >> 7, n2 = idx & 127;
      W2T[n2 * 256 + k2] = f2bf(W2[k2 * 128 + n2]);
    }
    if (idx < 256) bc[idx] = bu[idx] + bm[idx];
  }
}

// ---------------------------------------------------------------------------
// gather_user: one WAVE per batch row. Lane slice = 16 B; quad q handles
// nbr 4*it+q -> 13 wave-loads of 1 KB. Cross-quad shfl_xor reduce.
// ---------------------------------------------------------------------------
__global__ __launch_bounds__(256) void gather_user(
    const float* __restrict__ users, const int* __restrict__ nbr_ids,
    const __hip_bfloat16* __restrict__ tb, __hip_bfloat16* __restrict__ A_user) {
  int row  = (blockIdx.x << 2) + (threadIdx.x >> 6);
  int lane = threadIdx.x & 63;
  int quad = lane >> 4, sl = lane & 15;
  const int* nb = nbr_ids + row * NNBR;
  float acc[8] = {0.f, 0.f, 0.f, 0.f, 0.f, 0.f, 0.f, 0.f};
  #pragma unroll
  for (int it = 0; it < 13; ++it) {
    int j = it * 4 + quad;
    if (j < NNBR) {
      int id = nb[j];
      short8 v = *(const short8*)(tb + (size_t)id * FEAT + sl * 8);
      #pragma unroll
      for (int e = 0; e < 8; ++e) acc[e] += bfb2f(v[e]);
    }
  }
  __hip_bfloat16 o[8];
  #pragma unroll
  for (int e = 0; e < 8; ++e) {
    float v = acc[e];
    v += __shfl_xor(v, 16, 64);
    v += __shfl_xor(v, 32, 64);
    o[e] = f2bf(v * (1.f / NNBR));
  }
  if (quad == 0)
    *(short8*)(A_user + (size_t)row * 256 + 128 + sl * 8) = *(short8*)o;
  float2 uv = ((const float2*)(users + (size_t)row * FEAT))[lane];
  __hip_bfloat162 t0; t0.x = f2bf(uv.x); t0.y = f2bf(uv.y);
  ((__hip_bfloat162*)(A_user + (size_t)row * 256))[lane] = t0;
}

// ---------------------------------------------------------------------------
// layer: one GEMM layer on a 64-row LDS tile with B persistent in VGPRs.
//   Ain (LDS): 64 rows x K0, XOR-swizzled (16B slot s holds chunk s^(r&7)).
//   Wt: global [NCOL][K0] bf16 (L2-hot; ~16 KB/wave loaded ONCE per layer).
// 8 waves split N: wave w owns JN*16 cols (JN = NCOL/128).
// 4 iters x 16 rows: KK ds_read_b128 + 2*KK*JN MFMA; epilogue -> LDS
// (swizzled, 256-col) or global fp32 (128-col).
// ---------------------------------------------------------------------------
template <int K0, int NCOL, bool RELU, bool TOGLB>
__device__ __forceinline__ void layer(
    const __hip_bfloat16* Ain,
    const __hip_bfloat16* __restrict__ Wt, const float* __restrict__ bias,
    __hip_bfloat16* Olds, float* __restrict__ Oglb,
    int wid, int quad, int lrow) {
  constexpr int KK = K0 / 32;
  constexpr int JN = NCOL / 128;
  const int c0 = wid * JN * 16;

  short8 bfr[JN][KK];
  float  bv[JN];
  #pragma unroll
  for (int j = 0; j < JN; ++j) {
    #pragma unroll
    for (int kc = 0; kc < KK; ++kc)
      bfr[j][kc] = *(const short8*)(Wt + (size_t)(c0 + j * 16 + lrow) * K0 +
                                    kc * 32 + quad * 8);
    bv[j] = bias[c0 + j * 16 + lrow];
  }

  #pragma unroll
  for (int it = 0; it < 4; ++it) {
    int r = it * 16 + lrow;
    short8 af[KK];
    #pragma unroll
    for (int kc = 0; kc < KK; ++kc)
      af[kc] = *(const short8*)&Ain[r * K0 + (((kc * 4 + quad) ^ (r & 7)) << 3)];
    floatx4 pa[JN], pb[JN];
    #pragma unroll
    for (int j = 0; j < JN; ++j) { pa[j] = {}; pb[j] = {}; }
    #pragma unroll
    for (int kc = 0; kc < KK; kc += 2)
      #pragma unroll
      for (int j = 0; j < JN; ++j) {
        pa[j] = mfma16(af[kc],     bfr[j][kc],     pa[j]);
        pb[j] = mfma16(af[kc + 1], bfr[j][kc + 1], pb[j]);
      }
    #pragma unroll
    for (int j = 0; j < JN; ++j) {
      floatx4 a = pa[j] + pb[j];
      int col = c0 + j * 16 + lrow;
      #pragma unroll
      for (int rr = 0; rr < 4; ++rr) {
        int row = it * 16 + quad * 4 + rr;
        float v = a[rr] + bv[j];
        if (RELU) v = fmaxf(v, 0.f);
        if (TOGLB) {
          Oglb[(size_t)row * NCOL + col] = v;
        } else {
          int ch = col >> 3;
          Olds[row * 256 + (((ch ^ (row & 7)) << 3) | (col & 7))] = f2bf(v);
        }
      }
    }
  }
}

// ---------------------------------------------------------------------------
// fused_mlp: one block = 64 rows of stream s (0 user / 1 pos / 2 neg),
// all 3 layers. Row-locality makes this legal with NO grid sync.
// R4 failure mode (B restaged via LDS every 32-k: 54 vmcnt-drain barriers)
// is gone: B lives in VGPRs per layer (R9 structure), A/E/H live in LDS.
// Exactly 3 barriers per block. 768 blocks, 512 thr, 1 block/CU
// (launch_bounds(512,2) -> 256-VGPR cap; ~200 VGPRs used, B stays resident).
// Kills 3 launches + 96 MB of E/H global round-trips vs the R9 4-kernel split.
// ---------------------------------------------------------------------------
__global__ __launch_bounds__(512, 2) void fused_mlp(
    const __hip_bfloat16* __restrict__ A_user,
    const __hip_bfloat16* __restrict__ tb,
    const int* __restrict__ pos_ids, const int* __restrict__ neg_ids,
    const __hip_bfloat16* __restrict__ WcatT,
    const __hip_bfloat16* __restrict__ WmT,
    const __hip_bfloat16* __restrict__ W1T,
    const __hip_bfloat16* __restrict__ W2T,
    const float* __restrict__ bc, const float* __restrict__ bmv,
    const float* __restrict__ b1, const float* __restrict__ b2,
    float* __restrict__ out) {
  __shared__ __hip_bfloat16 A_lds[64 * 256];   // 32 KB: A, then H
  __shared__ __hip_bfloat16 E_lds[64 * 256];   // 32 KB: E

  const int t    = threadIdx.x;
  const int lane = t & 63, wid = t >> 6;       // wid 0..7
  const int quad = lane >> 4, lrow = lane & 15;
  const int s    = blockIdx.x % 3;
  const long m0  = (long)(blockIdx.x / 3) * 64;

  // ---- stage A tile (async DMA; drained by the first barrier) ----
  if (s == 0) {
    #pragma unroll
    for (int i = 0; i < 4; ++i) {
      int c = t + i * 512;                     // 2048 slots: r=c>>5, sl=c&31
      int r = c >> 5, sl = c & 31;
      gld16(A_user + ((size_t)(m0 + r) << 8) + ((sl ^ (r & 7)) << 3),
            A_lds + (c << 3));
    }
  } else {
    const int* ids = (s == 1) ? pos_ids : neg_ids;
    #pragma unroll
    for (int i = 0; i < 2; ++i) {
      int c = t + i * 512;                     // 1024 slots: r=c>>4, sl=c&15
      int r = c >> 4, sl = c & 15;
      int id = ids[m0 + r];
      gld16(tb + ((size_t)id << 7) + ((sl ^ (r & 7)) << 3),
            A_lds + (c << 3));
    }
  }
  __syncthreads();                             // A staged (vmcnt(0) drain)

  // ---- layer 0 -> E_lds (no relu) ----
  if (s == 0)
    layer<256, 256, false, false>(A_lds, WcatT, bc, E_lds, nullptr,
                                  wid, quad, lrow);
  else
    layer<128, 256, false, false>(A_lds, WmT, bmv, E_lds, nullptr,
                                  wid, quad, lrow);
  __syncthreads();                             // E complete (A reads done)

  // ---- layer 1: H = relu(E @ W1^T + b1) -> A_lds ----
  layer<256, 256, true, false>(E_lds, W1T, b1, A_lds, nullptr,
                               wid, quad, lrow);
  __syncthreads();                             // H complete

  // ---- layer 2: out = relu(H @ W2^T + b2) -> global fp32 ----
  layer<256, 128, true, true>(A_lds, W2T, b2, nullptr,
                              out + ((size_t)s * BATCH_N + m0) * 128,
                              wid, quad, lrow);
}

// ---------------------------------------------------------------------------
extern "C" void kernel_launch(void* const* d_in, const int* in_sizes, int n_in,
                              void* d_out, int out_size, void* d_ws, size_t ws_size,
                              hipStream_t stream) {
  const float* users   = (const float*)d_in[0];
  // d_in[1] pos_movies, d_in[2] neg_movies, d_in[3] user_ids: unused by ref
  const int*   pos_ids = (const int*)d_in[4];
  const int*   neg_ids = (const int*)d_in[5];
  const int*   nbr_ids = (const int*)d_in[6];
  const float* table   = (const float*)d_in[7];
  const float* Wu = (const float*)d_in[8];
  const float* bu = (const float*)d_in[9];
  const float* Wm = (const float*)d_in[10];
  const float* bm = (const float*)d_in[11];
  const float* W1 = (const float*)d_in[12];
  const float* b1 = (const float*)d_in[13];
  const float* W2 = (const float*)d_in[14];
  const float* b2 = (const float*)d_in[15];
  float* out = (float*)d_out;

  // workspace carve (all 256B aligned). Total ~34 MB.
  char* p = (char*)d_ws;
  auto carve = [&](size_t bytes) { char* r = p; p += (bytes + 255) & ~(size_t)255; return r; };
  __hip_bfloat16* tb     = (__hip_bfloat16*)carve((size_t)NUM_MOVIES_N * FEAT * 2);
  __hip_bfloat16* WcatT  = (__hip_bfloat16*)carve(256 * 256 * 2);
  __hip_bfloat16* WmT    = (__hip_bfloat16*)carve(256 * 128 * 2);
  __hip_bfloat16* W1T    = (__hip_bfloat16*)carve(256 * 256 * 2);
  __hip_bfloat16* W2T    = (__hip_bfloat16*)carve(128 * 256 * 2);
  float*          bc     = (float*)carve(256 * 4);
  __hip_bfloat16* A_user = (__hip_bfloat16*)carve((size_t)BATCH_N * 256 * 2);

  prep_all<<<CONV_BLOCKS + 256, 256, 0, stream>>>(
      table, tb, Wu, Wm, W1, W2, bu, bm, WcatT, WmT, W1T, W2T, bc);
  gather_user<<<BATCH_N / 4, 256, 0, stream>>>(users, nbr_ids, tb, A_user);
  fused_mlp<<<3 * BATCH_N / 64, 512, 0, stream>>>(
      A_user, tb, pos_ids, neg_ids, WcatT, WmT, W1T, W2T,
      bc, bm, b1, b2, out);
}

// Round 11
// 201.472 us; speedup vs baseline: 1.2377x; 1.0135x over previous
//
#include <hip/hip_runtime.h>
#include <hip/hip_bf16.h>

// Problem constants (from reference)
#define BATCH_N   16384
#define FEAT      128      // MOVIE_FEAT == USER_FEAT
#define NNBR      50
#define NUM_MOVIES_N 100000

typedef short  short8  __attribute__((ext_vector_type(8)));
typedef float  floatx4 __attribute__((ext_vector_type(4)));
typedef unsigned int u32;

__device__ __forceinline__ __hip_bfloat16 f2bf(float x) { return __float2bfloat16(x); }
__device__ __forceinline__ float bfb2f(short s) {
  union { u32 u; float f; } c; c.u = ((u32)(unsigned short)s) << 16; return c.f;
}

// async global->LDS 16B DMA. LDS dst must be wave-uniform base + lane*16
// (m104), so the XOR swizzle is applied to the SOURCE index.
__device__ __forceinline__ void gld16(const __hip_bfloat16* g, __hip_bfloat16* l) {
  __builtin_amdgcn_global_load_lds(
      (const __attribute__((address_space(1))) u32*)g,
      (__attribute__((address_space(3))) u32*)l, 16, 0, 0);
}

__device__ __forceinline__ floatx4 mfma16(short8 a, short8 b, floatx4 c) {
  return __builtin_amdgcn_mfma_f32_16x16x32_bf16(a, b, c, 0, 0, 0);
}

// ---------------------------------------------------------------------------
// prep_all: fused (a) fp32 movie_table -> bf16 copy and (b) bf16 transposed
// weights Wt[n][k] + fused bias bu+bm. One launch instead of two.
// blocks [0,6250): conv;  [6250,6506): weight prep.
// ---------------------------------------------------------------------------
#define CONV_BLOCKS (NUM_MOVIES_N * FEAT / (256 * 8))   // 6250
__global__ __launch_bounds__(256) void prep_all(
    const float* __restrict__ t, __hip_bfloat16* __restrict__ tb,
    const float* __restrict__ Wu, const float* __restrict__ Wm,
    const float* __restrict__ W1, const float* __restrict__ W2,
    const float* __restrict__ bu, const float* __restrict__ bm,
    __hip_bfloat16* __restrict__ WcatT, __hip_bfloat16* __restrict__ WmT,
    __hip_bfloat16* __restrict__ W1T,  __hip_bfloat16* __restrict__ W2T,
    float* __restrict__ bc) {
  int bid = blockIdx.x;
  if (bid < CONV_BLOCKS) {
    size_t i = ((size_t)bid * 256 + threadIdx.x) * 8;
    float4 v0 = *(const float4*)(t + i);
    float4 v1 = *(const float4*)(t + i + 4);
    __hip_bfloat16 o[8];
    o[0] = f2bf(v0.x); o[1] = f2bf(v0.y); o[2] = f2bf(v0.z); o[3] = f2bf(v0.w);
    o[4] = f2bf(v1.x); o[5] = f2bf(v1.y); o[6] = f2bf(v1.z); o[7] = f2bf(v1.w);
    *(short8*)(tb + i) = *(short8*)o;
  } else {
    int idx = (bid - CONV_BLOCKS) * 256 + threadIdx.x;   // 0..65535
    int n = idx & 255, k = idx >> 8;
    float v = (k < 128) ? Wu[k * 256 + n] : Wm[(k - 128) * 256 + n];
    WcatT[n * 256 + k] = f2bf(v);
    W1T[n * 256 + k]   = f2bf(W1[k * 256 + n]);
    if (k < 128) WmT[n * 128 + k] = f2bf(Wm[k * 256 + n]);
    if (idx < 32768) {
      int k2 = idx >> 7, n2 = idx & 127;
      W2T[n2 * 256 + k2] = f2bf(W2[k2 * 128 + n2]);
    }
    if (idx < 256) bc[idx] = bu[idx] + bm[idx];
  }
}

// ---------------------------------------------------------------------------
// gather_user: one WAVE per batch row. Lane slice = 16 B; quad q handles
// nbr 4*it+q -> 13 wave-loads of 1 KB. Cross-quad shfl_xor reduce.
// ---------------------------------------------------------------------------
__global__ __launch_bounds__(256) void gather_user(
    const float* __restrict__ users, const int* __restrict__ nbr_ids,
    const __hip_bfloat16* __restrict__ tb, __hip_bfloat16* __restrict__ A_user) {
  int row  = (blockIdx.x << 2) + (threadIdx.x >> 6);
  int lane = threadIdx.x & 63;
  int quad = lane >> 4, sl = lane & 15;
  const int* nb = nbr_ids + row * NNBR;
  float acc[8] = {0.f, 0.f, 0.f, 0.f, 0.f, 0.f, 0.f, 0.f};
  #pragma unroll
  for (int it = 0; it < 13; ++it) {
    int j = it * 4 + quad;
    if (j < NNBR) {
      int id = nb[j];
      short8 v = *(const short8*)(tb + (size_t)id * FEAT + sl * 8);
      #pragma unroll
      for (int e = 0; e < 8; ++e) acc[e] += bfb2f(v[e]);
    }
  }
  __hip_bfloat16 o[8];
  #pragma unroll
  for (int e = 0; e < 8; ++e) {
    float v = acc[e];
    v += __shfl_xor(v, 16, 64);
    v += __shfl_xor(v, 32, 64);
    o[e] = f2bf(v * (1.f / NNBR));
  }
  if (quad == 0)
    *(short8*)(A_user + (size_t)row * 256 + 128 + sl * 8) = *(short8*)o;
  float2 uv = ((const float2*)(users + (size_t)row * FEAT))[lane];
  __hip_bfloat162 t0; t0.x = f2bf(uv.x); t0.y = f2bf(uv.y);
  ((__hip_bfloat162*)(A_user + (size_t)row * 256))[lane] = t0;
}

// ---------------------------------------------------------------------------
// layer: one GEMM layer on a 64-row LDS tile with B persistent in VGPRs.
//   Ain (LDS): 64 rows x K0, XOR-swizzled (16B slot s holds chunk s^(r&7)).
//   Wt: global [NCOL][K0] bf16 (L2-hot; ~16 KB/wave loaded ONCE per layer).
// 8 waves split N: wave w owns JN*16 cols (JN = NCOL/128).
// 4 iters x 16 rows: KK ds_read_b128 + 2*KK*JN MFMA; epilogue -> LDS
// (swizzled, 256-col) or global fp32 (128-col).
// ---------------------------------------------------------------------------
template <int K0, int NCOL, bool RELU, bool TOGLB>
__device__ __forceinline__ void layer(
    const __hip_bfloat16* Ain,
    const __hip_bfloat16* __restrict__ Wt, const float* __restrict__ bias,
    __hip_bfloat16* Olds, float* __restrict__ Oglb,
    int wid, int quad, int lrow) {
  constexpr int KK = K0 / 32;
  constexpr int JN = NCOL / 128;
  const int c0 = wid * JN * 16;

  short8 bfr[JN][KK];
  float  bv[JN];
  #pragma unroll
  for (int j = 0; j < JN; ++j) {
    #pragma unroll
    for (int kc = 0; kc < KK; ++kc)
      bfr[j][kc] = *(const short8*)(Wt + (size_t)(c0 + j * 16 + lrow) * K0 +
                                    kc * 32 + quad * 8);
    bv[j] = bias[c0 + j * 16 + lrow];
  }

  #pragma unroll
  for (int it = 0; it < 4; ++it) {
    int r = it * 16 + lrow;
    short8 af[KK];
    #pragma unroll
    for (int kc = 0; kc < KK; ++kc)
      af[kc] = *(const short8*)&Ain[r * K0 + (((kc * 4 + quad) ^ (r & 7)) << 3)];
    floatx4 pa[JN], pb[JN];
    #pragma unroll
    for (int j = 0; j < JN; ++j) { pa[j] = {}; pb[j] = {}; }
    #pragma unroll
    for (int kc = 0; kc < KK; kc += 2)
      #pragma unroll
      for (int j = 0; j < JN; ++j) {
        pa[j] = mfma16(af[kc],     bfr[j][kc],     pa[j]);
        pb[j] = mfma16(af[kc + 1], bfr[j][kc + 1], pb[j]);
      }
    #pragma unroll
    for (int j = 0; j < JN; ++j) {
      floatx4 a = pa[j] + pb[j];
      int col = c0 + j * 16 + lrow;
      #pragma unroll
      for (int rr = 0; rr < 4; ++rr) {
        int row = it * 16 + quad * 4 + rr;
        float v = a[rr] + bv[j];
        if (RELU) v = fmaxf(v, 0.f);
        if (TOGLB) {
          Oglb[(size_t)row * NCOL + col] = v;
        } else {
          int ch = col >> 3;
          Olds[row * 256 + (((ch ^ (row & 7)) << 3) | (col & 7))] = f2bf(v);
        }
      }
    }
  }
}

// ---------------------------------------------------------------------------
// fused_mlp: one block = 64 rows of stream s (0 user / 1 pos / 2 neg),
// all 3 layers; B per layer in VGPRs, A/E/H in LDS; 3 barriers per block.
//
// R10 lesson: __launch_bounds__(512,2) only sets a MINIMUM waves/EU — the
// scheduler targeted 4 waves/SIMD, capped itself at 88 VGPRs, and sank the
// B-loads into the loop (MfmaUtil 10.7%). amdgpu_waves_per_eu(2,2) pins the
// occupancy target to exactly 2 waves/EU -> 256-VGPR budget -> the ~200-VGPR
// persistent-B working set stays resident.
// ---------------------------------------------------------------------------
__global__ __launch_bounds__(512)
__attribute__((amdgpu_waves_per_eu(2, 2)))
void fused_mlp(
    const __hip_bfloat16* __restrict__ A_user,
    const __hip_bfloat16* __restrict__ tb,
    const int* __restrict__ pos_ids, const int* __restrict__ neg_ids,
    const __hip_bfloat16* __restrict__ WcatT,
    const __hip_bfloat16* __restrict__ WmT,
    const __hip_bfloat16* __restrict__ W1T,
    const __hip_bfloat16* __restrict__ W2T,
    const float* __restrict__ bc, const float* __restrict__ bmv,
    const float* __restrict__ b1, const float* __restrict__ b2,
    float* __restrict__ out) {
  __shared__ __hip_bfloat16 A_lds[64 * 256];   // 32 KB: A, then H
  __shared__ __hip_bfloat16 E_lds[64 * 256];   // 32 KB: E

  const int t    = threadIdx.x;
  const int lane = t & 63, wid = t >> 6;       // wid 0..7
  const int quad = lane >> 4, lrow = lane & 15;
  const int s    = blockIdx.x % 3;
  const long m0  = (long)(blockIdx.x / 3) * 64;

  // ---- stage A tile (async DMA; drained by the first barrier) ----
  if (s == 0) {
    #pragma unroll
    for (int i = 0; i < 4; ++i) {
      int c = t + i * 512;                     // 2048 slots: r=c>>5, sl=c&31
      int r = c >> 5, sl = c & 31;
      gld16(A_user + ((size_t)(m0 + r) << 8) + ((sl ^ (r & 7)) << 3),
            A_lds + (c << 3));
    }
  } else {
    const int* ids = (s == 1) ? pos_ids : neg_ids;
    #pragma unroll
    for (int i = 0; i < 2; ++i) {
      int c = t + i * 512;                     // 1024 slots: r=c>>4, sl=c&15
      int r = c >> 4, sl = c & 15;
      int id = ids[m0 + r];
      gld16(tb + ((size_t)id << 7) + ((sl ^ (r & 7)) << 3),
            A_lds + (c << 3));
    }
  }
  __syncthreads();                             // A staged (vmcnt(0) drain)

  // ---- layer 0 -> E_lds (no relu) ----
  if (s == 0)
    layer<256, 256, false, false>(A_lds, WcatT, bc, E_lds, nullptr,
                                  wid, quad, lrow);
  else
    layer<128, 256, false, false>(A_lds, WmT, bmv, E_lds, nullptr,
                                  wid, quad, lrow);
  __syncthreads();                             // E complete (A reads done)

  // ---- layer 1: H = relu(E @ W1^T + b1) -> A_lds ----
  layer<256, 256, true, false>(E_lds, W1T, b1, A_lds, nullptr,
                               wid, quad, lrow);
  __syncthreads();                             // H complete

  // ---- layer 2: out = relu(H @ W2^T + b2) -> global fp32 ----
  layer<256, 128, true, true>(A_lds, W2T, b2, nullptr,
                              out + ((size_t)s * BATCH_N + m0) * 128,
                              wid, quad, lrow);
}

// ---------------------------------------------------------------------------
extern "C" void kernel_launch(void* const* d_in, const int* in_sizes, int n_in,
                              void* d_out, int out_size, void* d_ws, size_t ws_size,
                              hipStream_t stream) {
  const float* users   = (const float*)d_in[0];
  // d_in[1] pos_movies, d_in[2] neg_movies, d_in[3] user_ids: unused by ref
  const int*   pos_ids = (const int*)d_in[4];
  const int*   neg_ids = (const int*)d_in[5];
  const int*   nbr_ids = (const int*)d_in[6];
  const float* table   = (const float*)d_in[7];
  const float* Wu = (const float*)d_in[8];
  const float* bu = (const float*)d_in[9];
  const float* Wm = (const float*)d_in[10];
  const float* bm = (const float*)d_in[11];
  const float* W1 = (const float*)d_in[12];
  const float* b1 = (const float*)d_in[13];
  const float* W2 = (const float*)d_in[14];
  const float* b2 = (const float*)d_in[15];
  float* out = (float*)d_out;

  // workspace carve (all 256B aligned). Total ~34 MB.
  char* p = (char*)d_ws;
  auto carve = [&](size_t bytes) { char* r = p; p += (bytes + 255) & ~(size_t)255; return r; };
  __hip_bfloat16* tb     = (__hip_bfloat16*)carve((size_t)NUM_MOVIES_N * FEAT * 2);
  __hip_bfloat16* WcatT  = (__hip_bfloat16*)carve(256 * 256 * 2);
  __hip_bfloat16* WmT    = (__hip_bfloat16*)carve(256 * 128 * 2);
  __hip_bfloat16* W1T    = (__hip_bfloat16*)carve(256 * 256 * 2);
  __hip_bfloat16* W2T    = (__hip_bfloat16*)carve(128 * 256 * 2);
  float*          bc     = (float*)carve(256 * 4);
  __hip_bfloat16* A_user = (__hip_bfloat16*)carve((size_t)BATCH_N * 256 * 2);

  prep_all<<<CONV_BLOCKS + 256, 256, 0, stream>>>(
      table, tb, Wu, Wm, W1, W2, bu, bm, WcatT, WmT, W1T, W2T, bc);
  gather_user<<<BATCH_N / 4, 256, 0, stream>>>(users, nbr_ids, tb, A_user);
  fused_mlp<<<3 * BATCH_N / 64, 512, 0, stream>>>(
      A_user, tb, pos_ids, neg_ids, WcatT, WmT, W1T, W2T,
      bc, bm, b1, b2, out);
}